// Round 2
// baseline (34536.353 us; speedup 1.0000x reference)
//
#include <hip/hip_runtime.h>
#include <hip/hip_cooperative_groups.h>

namespace cg = cooperative_groups;

#define S_ 512
#define B_ 64
#define I_ 512
#define H_ 1024
#define O_ 512
#define C_ 1536   // I_ + H_
#define NG_ 4096  // 4*H_

typedef unsigned short u16;
typedef __attribute__((ext_vector_type(8))) short bf16x8;
typedef __attribute__((ext_vector_type(8))) unsigned short u16x8;
typedef __attribute__((ext_vector_type(4))) float f32x4;

__device__ __forceinline__ u16 f2bf(float f) {
    union { float f; unsigned int u; } v; v.f = f;
    unsigned int u = v.u;
    unsigned int r = (u + 0x7fffu + ((u >> 16) & 1u)) >> 16;
    return (u16)r;
}
__device__ __forceinline__ float bf2f(u16 h) {
    union { unsigned int u; float f; } v; v.u = ((unsigned int)h) << 16;
    return v.f;
}
__device__ __forceinline__ float sigm(float x) { return 1.0f / (1.0f + __expf(-x)); }

// ---- packing kernels -------------------------------------------------------

__global__ void k_pack_w(const float* __restrict__ Wf, const float* __restrict__ Wi,
                         const float* __restrict__ Wo, const float* __restrict__ Wg,
                         u16* __restrict__ Wall) {
    size_t i8 = ((size_t)blockIdx.x * blockDim.x + threadIdx.x) * 8;
    if (i8 >= (size_t)NG_ * C_) return;
    size_t n = i8 / C_;
    size_t k = i8 - n * C_;
    const float* Ws[4] = {Wf, Wi, Wo, Wg};
    const float* src = Ws[n >> 10] + (n & 1023) * C_ + k;
    u16x8 o;
#pragma unroll
    for (int j = 0; j < 8; j++) o[j] = f2bf(src[j]);
    *(u16x8*)(Wall + i8) = o;
}

__global__ void k_pack_wy(const float* __restrict__ Wy,
                          u16* __restrict__ hi, u16* __restrict__ lo) {
    size_t i8 = ((size_t)blockIdx.x * blockDim.x + threadIdx.x) * 8;
    if (i8 >= (size_t)O_ * H_) return;
    u16x8 oh, ol;
#pragma unroll
    for (int j = 0; j < 8; j++) {
        float v = Wy[i8 + j];
        oh[j] = f2bf(v);
        ol[j] = f2bf(v - bf2f(oh[j]));
    }
    *(u16x8*)(hi + i8) = oh;
    *(u16x8*)(lo + i8) = ol;
}

__global__ void k_pack_x(const float* __restrict__ x, u16* __restrict__ xb) {
    size_t i8 = ((size_t)blockIdx.x * blockDim.x + threadIdx.x) * 8;
    if (i8 >= (size_t)S_ * B_ * I_) return;
    u16x8 o;
#pragma unroll
    for (int j = 0; j < 8; j++) o[j] = f2bf(x[i8 + j]);
    *(u16x8*)(xb + i8) = o;
}

// ---- persistent cooperative LSTM -------------------------------------------
// 256 blocks x 256 threads. Block b owns hidden units [4b, 4b+4) for all 4
// gates = 16 rows of Wall, resident in LDS for all 512 steps. Cell state c:
// one fp32 register per thread. Per step: 64x16 gate tile via MFMA (wave w =
// batch rows [16w,16w+16)), LDS transpose, cell update, write h slice, grid sync.
__global__ __launch_bounds__(256) void k_lstm(
    const u16* __restrict__ Wall,   // [4096][1536] bf16
    const u16* __restrict__ xbf,    // [S][64][512] bf16
    const float* __restrict__ bfv, const float* __restrict__ biv,
    const float* __restrict__ bov, const float* __restrict__ bgv,
    u16* __restrict__ hhi,          // [S+1][64][1024] bf16
    u16* __restrict__ hlo)          // [S+1][64][1024] bf16 residual
{
    cg::grid_group grid = cg::this_grid();

    const int tid = threadIdx.x;
    const int wv = tid >> 6;         // wave = batch strip
    const int lane = tid & 63;
    const int la = lane & 15;        // A-row (batch) / B-col (n) / C-col
    const int q = lane >> 4;         // k-group
    const int kg = q * 8;
    const int blk = blockIdx.x;

    // --- load this block's 16 W rows into LDS (row n = gate(n>>2), jj(n&3)) ---
    __shared__ u16 Ws[16][C_ + 8];   // pad +8 elems keeps b128 reads spread
    __shared__ float gl[64][17];
#pragma unroll 1
    for (int r = 0; r < 16; r++) {
        const u16* src = Wall + ((size_t)((r >> 2) * H_ + blk * 4 + (r & 3))) * C_;
        for (int c = tid; c < C_ / 8; c += 256)
            *(u16x8*)(&Ws[r][c * 8]) = *(const u16x8*)(src + c * 8);
    }

    // per-thread cell state + biases (thread -> (batch b, hidden jj))
    const int b = tid >> 2;
    const int jj = tid & 3;
    const int j = blk * 4 + jj;
    const float bf_r = bfv[j], bi_r = biv[j], bo_r = bov[j], bg_r = bgv[j];
    float creg = 0.0f;

    __syncthreads();
    grid.sync();   // ensure h_0 memset + packs complete everywhere

    for (int t = 0; t < S_; t++) {
        const u16* xt = xbf + (size_t)t * (B_ * I_) + (size_t)(wv * 16 + la) * I_ + kg;
        const u16* hp = hhi + (size_t)t * (B_ * H_) + (size_t)(wv * 16 + la) * H_ + kg;

        f32x4 acc0 = (f32x4){0.f, 0.f, 0.f, 0.f};
        f32x4 acc1 = (f32x4){0.f, 0.f, 0.f, 0.f};

        // x part: K = 512 (16 chunks of 32)
#pragma unroll 4
        for (int kc = 0; kc < 16; kc += 2) {
            bf16x8 a0 = *(const bf16x8*)(xt + kc * 32);
            bf16x8 b0 = *(const bf16x8*)(&Ws[la][kc * 32 + kg]);
            acc0 = __builtin_amdgcn_mfma_f32_16x16x32_bf16(a0, b0, acc0, 0, 0, 0);
            bf16x8 a1 = *(const bf16x8*)(xt + kc * 32 + 32);
            bf16x8 b1 = *(const bf16x8*)(&Ws[la][kc * 32 + 32 + kg]);
            acc1 = __builtin_amdgcn_mfma_f32_16x16x32_bf16(a1, b1, acc1, 0, 0, 0);
        }
        // h part: K = 1024 (32 chunks of 32)
#pragma unroll 4
        for (int kc = 0; kc < 32; kc += 2) {
            bf16x8 a0 = *(const bf16x8*)(hp + kc * 32);
            bf16x8 b0 = *(const bf16x8*)(&Ws[la][I_ + kc * 32 + kg]);
            acc0 = __builtin_amdgcn_mfma_f32_16x16x32_bf16(a0, b0, acc0, 0, 0, 0);
            bf16x8 a1 = *(const bf16x8*)(hp + kc * 32 + 32);
            bf16x8 b1 = *(const bf16x8*)(&Ws[la][I_ + kc * 32 + 32 + kg]);
            acc1 = __builtin_amdgcn_mfma_f32_16x16x32_bf16(a1, b1, acc1, 0, 0, 0);
        }

        // C-layout: col = lane&15, row = (lane>>4)*4 + r  (batch row within strip)
#pragma unroll
        for (int r = 0; r < 4; r++)
            gl[wv * 16 + q * 4 + r][la] = acc0[r] + acc1[r];
        __syncthreads();

        float fg = sigm(gl[b][0 + jj] + bf_r);
        float ig = sigm(gl[b][4 + jj] + bi_r);
        float og = sigm(gl[b][8 + jj] + bo_r);
        float gg = tanhf(gl[b][12 + jj] + bg_r);
        creg = fg * creg + ig * gg;
        float hn = og * tanhf(creg);
        u16 hb = f2bf(hn);
        size_t oa = (size_t)(t + 1) * (B_ * H_) + (size_t)b * H_ + j;
        hhi[oa] = hb;
        hlo[oa] = f2bf(hn - bf2f(hb));

        __threadfence();
        grid.sync();
    }
}

// ---- fallback per-step kernel (round-1 path, used only if coop launch fails)
__global__ __launch_bounds__(256) void k_step(
    const u16* __restrict__ Wall, const u16* __restrict__ xbf,
    const float* __restrict__ bfv, const float* __restrict__ biv,
    const float* __restrict__ bov, const float* __restrict__ bgv,
    u16* __restrict__ hhi, u16* __restrict__ hlo,
    float* __restrict__ cst, int t)
{
    const int tid = threadIdx.x;
    const int wv = tid >> 6;
    const int lane = tid & 63;
    const int la = lane & 15;
    const int kg = (lane >> 4) * 8;
    const int j0 = blockIdx.x * 16;

    const u16* xt = xbf + (size_t)t * (B_ * I_);
    const u16* hp = hhi + (size_t)t * (B_ * H_);
    const u16* bp = Wall + (size_t)(wv * H_ + j0 + la) * C_ + kg;

    f32x4 acc[4];
#pragma unroll
    for (int m = 0; m < 4; m++) acc[m] = (f32x4){0.f, 0.f, 0.f, 0.f};

    for (int k = 0; k < I_; k += 32) {
        bf16x8 bb = *(const bf16x8*)(bp + k);
#pragma unroll
        for (int m = 0; m < 4; m++) {
            bf16x8 aa = *(const bf16x8*)(xt + (size_t)(m * 16 + la) * I_ + k + kg);
            acc[m] = __builtin_amdgcn_mfma_f32_16x16x32_bf16(aa, bb, acc[m], 0, 0, 0);
        }
    }
    const u16* bp2 = bp + I_;
    for (int k = 0; k < H_; k += 32) {
        bf16x8 bb = *(const bf16x8*)(bp2 + k);
#pragma unroll
        for (int m = 0; m < 4; m++) {
            bf16x8 aa = *(const bf16x8*)(hp + (size_t)(m * 16 + la) * H_ + k + kg);
            acc[m] = __builtin_amdgcn_mfma_f32_16x16x32_bf16(aa, bb, acc[m], 0, 0, 0);
        }
    }

    __shared__ float gl[4][64][16];
#pragma unroll
    for (int m = 0; m < 4; m++)
#pragma unroll
        for (int r = 0; r < 4; r++)
            gl[wv][m * 16 + (lane >> 4) * 4 + r][la] = acc[m][r];
    __syncthreads();

    u16* ho = hhi + (size_t)(t + 1) * (B_ * H_);
    u16* lo = hlo + (size_t)(t + 1) * (B_ * H_);
    for (int e = tid; e < 1024; e += 256) {
        int b = e >> 4, jj = e & 15;
        int j = j0 + jj;
        float f = sigm(gl[0][b][jj] + bfv[j]);
        float i = sigm(gl[1][b][jj] + biv[j]);
        float o = sigm(gl[2][b][jj] + bov[j]);
        float g = tanhf(gl[3][b][jj] + bgv[j]);
        float cn = f * cst[b * H_ + j] + i * g;
        float hn = o * tanhf(cn);
        cst[b * H_ + j] = cn;
        u16 hb = f2bf(hn);
        ho[b * H_ + j] = hb;
        lo[b * H_ + j] = f2bf(hn - bf2f(hb));
    }
}

// ---- final projection: out = H_all @ Wy^T + by (bf16 hi/lo, ~fp32 quality)
__global__ __launch_bounds__(256) void k_pred(
    const u16* __restrict__ ah, const u16* __restrict__ al,
    const u16* __restrict__ wyh, const u16* __restrict__ wyl,
    const float* __restrict__ by, float* __restrict__ out)
{
    const int tid = threadIdx.x;
    const int wv = tid >> 6;
    const int lane = tid & 63;
    const int la = lane & 15;
    const int kg = (lane >> 4) * 8;
    const int m0 = blockIdx.x * 64;
    const int n0 = blockIdx.y * 64 + wv * 16;

    const u16* bh = wyh + (size_t)(n0 + la) * H_ + kg;
    const u16* bl = wyl + (size_t)(n0 + la) * H_ + kg;

    f32x4 acc[4];
#pragma unroll
    for (int m = 0; m < 4; m++) acc[m] = (f32x4){0.f, 0.f, 0.f, 0.f};

    for (int k = 0; k < H_; k += 32) {
        bf16x8 bhh = *(const bf16x8*)(bh + k);
        bf16x8 bll = *(const bf16x8*)(bl + k);
#pragma unroll
        for (int m = 0; m < 4; m++) {
            size_t arow = (size_t)(m0 + m * 16 + la);
            bf16x8 aa  = *(const bf16x8*)(ah + arow * H_ + k + kg);
            bf16x8 aal = *(const bf16x8*)(al + arow * H_ + k + kg);
            acc[m] = __builtin_amdgcn_mfma_f32_16x16x32_bf16(aal, bhh, acc[m], 0, 0, 0);
            acc[m] = __builtin_amdgcn_mfma_f32_16x16x32_bf16(aa, bll, acc[m], 0, 0, 0);
            acc[m] = __builtin_amdgcn_mfma_f32_16x16x32_bf16(aa, bhh, acc[m], 0, 0, 0);
        }
    }

#pragma unroll
    for (int m = 0; m < 4; m++)
#pragma unroll
        for (int r = 0; r < 4; r++) {
            int row = m0 + m * 16 + (lane >> 4) * 4 + r;
            int col = n0 + la;
            out[(size_t)row * O_ + col] = acc[m][r] + by[col];
        }
}

// ---- host ------------------------------------------------------------------

extern "C" void kernel_launch(void* const* d_in, const int* in_sizes, int n_in,
                              void* d_out, int out_size, void* d_ws, size_t ws_size,
                              hipStream_t stream) {
    const float* x   = (const float*)d_in[0];
    const float* Wf  = (const float*)d_in[1];
    const float* bfv = (const float*)d_in[2];
    const float* Wi  = (const float*)d_in[3];
    const float* biv = (const float*)d_in[4];
    const float* Wo  = (const float*)d_in[5];
    const float* bov = (const float*)d_in[6];
    const float* Wg  = (const float*)d_in[7];
    const float* bgv = (const float*)d_in[8];
    const float* Wy  = (const float*)d_in[9];
    const float* by  = (const float*)d_in[10];
    float* out = (float*)d_out;

    char* ws = (char*)d_ws;
    size_t off = 0;
    auto alloc = [&](size_t bytes) {
        char* p = ws + off;
        off += (bytes + 255) & ~(size_t)255;
        return p;
    };
    u16*   Wall = (u16*)alloc((size_t)NG_ * C_ * 2);
    u16*   Wyhi = (u16*)alloc((size_t)O_ * H_ * 2);
    u16*   Wylo = (u16*)alloc((size_t)O_ * H_ * 2);
    u16*   xbf  = (u16*)alloc((size_t)S_ * B_ * I_ * 2);
    float* cst  = (float*)alloc((size_t)B_ * H_ * 4);
    u16*   hhi  = (u16*)alloc((size_t)(S_ + 1) * B_ * H_ * 2);
    u16*   hlo  = (u16*)alloc((size_t)(S_ + 1) * B_ * H_ * 2);

    (void)hipMemsetAsync(cst, 0, (size_t)B_ * H_ * 4, stream);
    (void)hipMemsetAsync(hhi, 0, (size_t)B_ * H_ * 2, stream);

    k_pack_w <<<3072, 256, 0, stream>>>(Wf, Wi, Wo, Wg, Wall);
    k_pack_wy<<<256,  256, 0, stream>>>(Wy, Wyhi, Wylo);
    k_pack_x <<<8192, 256, 0, stream>>>(x, xbf);

    void* args[] = {(void*)&Wall, (void*)&xbf, (void*)&bfv, (void*)&biv,
                    (void*)&bov, (void*)&bgv, (void*)&hhi, (void*)&hlo};
    hipError_t rc = hipLaunchCooperativeKernel((void*)k_lstm, dim3(256), dim3(256),
                                               args, 0, stream);
    if (rc != hipSuccess) {
        // deterministic fallback: per-step launches (round-1 path)
        for (int t = 0; t < S_; t++)
            k_step<<<64, 256, 0, stream>>>(Wall, xbf, bfv, biv, bov, bgv,
                                           hhi, hlo, cst, t);
    }

    k_pred<<<dim3(512, 8), 256, 0, stream>>>(hhi + (size_t)B_ * H_, hlo + (size_t)B_ * H_,
                                             Wyhi, Wylo, by, out);
}

// Round 3
// 6230.002 us; speedup vs baseline: 5.5436x; 5.5436x over previous
//
#include <hip/hip_runtime.h>

#define S_ 512
#define B_ 64
#define I_ 512
#define H_ 1024
#define O_ 512
#define C_ 1536   // I_ + H_
#define NG_ 4096  // 4*H_

typedef unsigned short u16;
typedef __attribute__((ext_vector_type(8))) short bf16x8;
typedef __attribute__((ext_vector_type(8))) unsigned short u16x8;
typedef __attribute__((ext_vector_type(4))) float f32x4;

__device__ __forceinline__ u16 f2bf(float f) {
    union { float f; unsigned int u; } v; v.f = f;
    unsigned int u = v.u;
    unsigned int r = (u + 0x7fffu + ((u >> 16) & 1u)) >> 16;
    return (u16)r;
}
__device__ __forceinline__ float bf2f(u16 h) {
    union { unsigned int u; float f; } v; v.u = ((unsigned int)h) << 16;
    return v.f;
}
__device__ __forceinline__ float sigm(float x) { return 1.0f / (1.0f + __expf(-x)); }

// ---- packing kernels -------------------------------------------------------

__global__ void k_pack_w(const float* __restrict__ Wf, const float* __restrict__ Wi,
                         const float* __restrict__ Wo, const float* __restrict__ Wg,
                         u16* __restrict__ Wall) {
    size_t i8 = ((size_t)blockIdx.x * blockDim.x + threadIdx.x) * 8;
    if (i8 >= (size_t)NG_ * C_) return;
    size_t n = i8 / C_;
    size_t k = i8 - n * C_;
    const float* Ws[4] = {Wf, Wi, Wo, Wg};
    const float* src = Ws[n >> 10] + (n & 1023) * C_ + k;
    u16x8 o;
#pragma unroll
    for (int j = 0; j < 8; j++) o[j] = f2bf(src[j]);
    *(u16x8*)(Wall + i8) = o;
}

__global__ void k_pack_wy(const float* __restrict__ Wy,
                          u16* __restrict__ hi, u16* __restrict__ lo) {
    size_t i8 = ((size_t)blockIdx.x * blockDim.x + threadIdx.x) * 8;
    if (i8 >= (size_t)O_ * H_) return;
    u16x8 oh, ol;
#pragma unroll
    for (int j = 0; j < 8; j++) {
        float v = Wy[i8 + j];
        oh[j] = f2bf(v);
        ol[j] = f2bf(v - bf2f(oh[j]));
    }
    *(u16x8*)(hi + i8) = oh;
    *(u16x8*)(lo + i8) = ol;
}

__global__ void k_pack_x(const float* __restrict__ x, u16* __restrict__ xb) {
    size_t i8 = ((size_t)blockIdx.x * blockDim.x + threadIdx.x) * 8;
    if (i8 >= (size_t)S_ * B_ * I_) return;
    u16x8 o;
#pragma unroll
    for (int j = 0; j < 8; j++) o[j] = f2bf(x[i8 + j]);
    *(u16x8*)(xb + i8) = o;
}

// ---- one LSTM time step, K-split across 8 waves -----------------------------
// 256 blocks x 512 threads. Block owns hidden units [4*blk, 4*blk+4) for all
// 4 gates = 16 Wall rows (row r: gate r>>2, unit r&3). Wave w handles
// K range [192w, 192w+192) of C=1536 (x cols 0..511, h cols 512..1535);
// 6 fully-unrolled K-chunks of 32 -> ~30 independent 16B loads per wave issue
// before the first wait (one latency burst). Partials reduced via LDS, cell
// update + h hi/lo store in-block. c state in global fp32.
__global__ __launch_bounds__(512, 2) void k_step2(
    const u16* __restrict__ Wall,   // [4096][1536] bf16
    const u16* __restrict__ xbf,    // [S][64][512] bf16
    const float* __restrict__ bfv, const float* __restrict__ biv,
    const float* __restrict__ bov, const float* __restrict__ bgv,
    u16* __restrict__ hhi,          // [S+1][64][1024] bf16
    u16* __restrict__ hlo,          // [S+1][64][1024] bf16 residual
    float* __restrict__ cst,        // [64][1024] fp32
    int t)
{
    const int tid = threadIdx.x;
    const int w = tid >> 6;          // wave 0..7 -> K range
    const int lane = tid & 63;
    const int la = lane & 15;        // A-row(batch) / B-row(gate-col) / C-col
    const int q = lane >> 4;         // quad -> k sub-offset, C row group
    const int blk = blockIdx.x;

    const u16* xt = xbf + (size_t)t * (B_ * I_);
    const u16* hp = hhi + (size_t)t * (B_ * H_);
    // this lane's B row: gate la>>2, unit la&3
    const u16* brow = Wall + (size_t)((la >> 2) * H_ + blk * 4 + (la & 3)) * C_;

    f32x4 acc[4];
#pragma unroll
    for (int m = 0; m < 4; m++) acc[m] = (f32x4){0.f, 0.f, 0.f, 0.f};

    const int kw = w * 192;
#pragma unroll
    for (int c = 0; c < 6; c++) {
        const int k0 = kw + c * 32;             // wave-uniform
        const bool inx = (k0 < I_);
        const u16* abase = inx ? (xt + k0) : (hp + (k0 - I_));
        const int astride = inx ? I_ : H_;
        bf16x8 bb = *(const bf16x8*)(brow + k0 + q * 8);
#pragma unroll
        for (int m = 0; m < 4; m++) {
            bf16x8 aa = *(const bf16x8*)(abase + (size_t)(m * 16 + la) * astride + q * 8);
            acc[m] = __builtin_amdgcn_mfma_f32_16x16x32_bf16(aa, bb, acc[m], 0, 0, 0);
        }
    }

    // reduce 8 wave-partials through LDS
    __shared__ float gl[8][64][17];
#pragma unroll
    for (int m = 0; m < 4; m++)
#pragma unroll
        for (int r = 0; r < 4; r++)
            gl[w][m * 16 + q * 4 + r][la] = acc[m][r];
    __syncthreads();

    if (tid < 256) {
        const int b = tid >> 2;      // batch row
        const int u = tid & 3;       // unit within block
        const int j = blk * 4 + u;   // global hidden index
        float s0 = 0.f, s1 = 0.f, s2 = 0.f, s3 = 0.f;
#pragma unroll
        for (int ww = 0; ww < 8; ww++) {
            s0 += gl[ww][b][0 + u];
            s1 += gl[ww][b][4 + u];
            s2 += gl[ww][b][8 + u];
            s3 += gl[ww][b][12 + u];
        }
        float fg = sigm(s0 + bfv[j]);
        float ig = sigm(s1 + biv[j]);
        float og = sigm(s2 + bov[j]);
        float gg = tanhf(s3 + bgv[j]);
        float cn = fg * cst[(size_t)b * H_ + j] + ig * gg;
        float hn = og * tanhf(cn);
        cst[(size_t)b * H_ + j] = cn;
        u16 hb = f2bf(hn);
        size_t oa = (size_t)(t + 1) * (B_ * H_) + (size_t)b * H_ + j;
        hhi[oa] = hb;
        hlo[oa] = f2bf(hn - bf2f(hb));
    }
}

// ---- final projection: out = H_all @ Wy^T + by (bf16 hi/lo, ~fp32 quality)
__global__ __launch_bounds__(256) void k_pred(
    const u16* __restrict__ ah, const u16* __restrict__ al,
    const u16* __restrict__ wyh, const u16* __restrict__ wyl,
    const float* __restrict__ by, float* __restrict__ out)
{
    const int tid = threadIdx.x;
    const int wv = tid >> 6;
    const int lane = tid & 63;
    const int la = lane & 15;
    const int kg = (lane >> 4) * 8;
    const int m0 = blockIdx.x * 64;
    const int n0 = blockIdx.y * 64 + wv * 16;

    const u16* bh = wyh + (size_t)(n0 + la) * H_ + kg;
    const u16* bl = wyl + (size_t)(n0 + la) * H_ + kg;

    f32x4 acc[4];
#pragma unroll
    for (int m = 0; m < 4; m++) acc[m] = (f32x4){0.f, 0.f, 0.f, 0.f};

    for (int k = 0; k < H_; k += 32) {
        bf16x8 bhh = *(const bf16x8*)(bh + k);
        bf16x8 bll = *(const bf16x8*)(bl + k);
#pragma unroll
        for (int m = 0; m < 4; m++) {
            size_t arow = (size_t)(m0 + m * 16 + la);
            bf16x8 aa  = *(const bf16x8*)(ah + arow * H_ + k + kg);
            bf16x8 aal = *(const bf16x8*)(al + arow * H_ + k + kg);
            acc[m] = __builtin_amdgcn_mfma_f32_16x16x32_bf16(aal, bhh, acc[m], 0, 0, 0);
            acc[m] = __builtin_amdgcn_mfma_f32_16x16x32_bf16(aa, bll, acc[m], 0, 0, 0);
            acc[m] = __builtin_amdgcn_mfma_f32_16x16x32_bf16(aa, bhh, acc[m], 0, 0, 0);
        }
    }

#pragma unroll
    for (int m = 0; m < 4; m++)
#pragma unroll
        for (int r = 0; r < 4; r++) {
            int row = m0 + m * 16 + (lane >> 4) * 4 + r;
            int col = n0 + la;
            out[(size_t)row * O_ + col] = acc[m][r] + by[col];
        }
}

// ---- host ------------------------------------------------------------------

extern "C" void kernel_launch(void* const* d_in, const int* in_sizes, int n_in,
                              void* d_out, int out_size, void* d_ws, size_t ws_size,
                              hipStream_t stream) {
    const float* x   = (const float*)d_in[0];
    const float* Wf  = (const float*)d_in[1];
    const float* bfv = (const float*)d_in[2];
    const float* Wi  = (const float*)d_in[3];
    const float* biv = (const float*)d_in[4];
    const float* Wo  = (const float*)d_in[5];
    const float* bov = (const float*)d_in[6];
    const float* Wg  = (const float*)d_in[7];
    const float* bgv = (const float*)d_in[8];
    const float* Wy  = (const float*)d_in[9];
    const float* by  = (const float*)d_in[10];
    float* out = (float*)d_out;

    char* ws = (char*)d_ws;
    size_t off = 0;
    auto alloc = [&](size_t bytes) {
        char* p = ws + off;
        off += (bytes + 255) & ~(size_t)255;
        return p;
    };
    u16*   Wall = (u16*)alloc((size_t)NG_ * C_ * 2);
    u16*   Wyhi = (u16*)alloc((size_t)O_ * H_ * 2);
    u16*   Wylo = (u16*)alloc((size_t)O_ * H_ * 2);
    u16*   xbf  = (u16*)alloc((size_t)S_ * B_ * I_ * 2);
    float* cst  = (float*)alloc((size_t)B_ * H_ * 4);
    u16*   hhi  = (u16*)alloc((size_t)(S_ + 1) * B_ * H_ * 2);
    u16*   hlo  = (u16*)alloc((size_t)(S_ + 1) * B_ * H_ * 2);

    (void)hipMemsetAsync(cst, 0, (size_t)B_ * H_ * 4, stream);
    (void)hipMemsetAsync(hhi, 0, (size_t)B_ * H_ * 2, stream);

    k_pack_w <<<3072, 256, 0, stream>>>(Wf, Wi, Wo, Wg, Wall);
    k_pack_wy<<<256,  256, 0, stream>>>(Wy, Wyhi, Wylo);
    k_pack_x <<<8192, 256, 0, stream>>>(x, xbf);

    for (int t = 0; t < S_; t++)
        k_step2<<<256, 512, 0, stream>>>(Wall, xbf, bfv, biv, bov, bgv,
                                         hhi, hlo, cst, t);

    k_pred<<<dim3(512, 8), 256, 0, stream>>>(hhi + (size_t)B_ * H_, hlo + (size_t)B_ * H_,
                                             Wyhi, Wylo, by, out);
}

// Round 4
// 5643.608 us; speedup vs baseline: 6.1196x; 1.1039x over previous
//
#include <hip/hip_runtime.h>

#define S_ 512
#define B_ 64
#define I_ 512
#define H_ 1024
#define O_ 512
#define C_ 1536   // I_ + H_
#define NG_ 4096  // 4*H_

typedef unsigned short u16;
typedef __attribute__((ext_vector_type(8))) short bf16x8;
typedef __attribute__((ext_vector_type(8))) unsigned short u16x8;
typedef __attribute__((ext_vector_type(4))) float f32x4;

__device__ __forceinline__ u16 f2bf(float f) {
    union { float f; unsigned int u; } v; v.f = f;
    unsigned int u = v.u;
    unsigned int r = (u + 0x7fffu + ((u >> 16) & 1u)) >> 16;
    return (u16)r;
}
__device__ __forceinline__ float bf2f(u16 h) {
    union { unsigned int u; float f; } v; v.u = ((unsigned int)h) << 16;
    return v.f;
}
__device__ __forceinline__ float sigm(float x) { return 1.0f / (1.0f + __expf(-x)); }

// ---- packing kernels -------------------------------------------------------

__global__ void k_pack_w(const float* __restrict__ Wf, const float* __restrict__ Wi,
                         const float* __restrict__ Wo, const float* __restrict__ Wg,
                         u16* __restrict__ Wall) {
    size_t i8 = ((size_t)blockIdx.x * blockDim.x + threadIdx.x) * 8;
    if (i8 >= (size_t)NG_ * C_) return;
    size_t n = i8 / C_;
    size_t k = i8 - n * C_;
    const float* Ws[4] = {Wf, Wi, Wo, Wg};
    const float* src = Ws[n >> 10] + (n & 1023) * C_ + k;
    u16x8 o;
#pragma unroll
    for (int j = 0; j < 8; j++) o[j] = f2bf(src[j]);
    *(u16x8*)(Wall + i8) = o;
}

__global__ void k_pack_wy(const float* __restrict__ Wy,
                          u16* __restrict__ hi, u16* __restrict__ lo) {
    size_t i8 = ((size_t)blockIdx.x * blockDim.x + threadIdx.x) * 8;
    if (i8 >= (size_t)O_ * H_) return;
    u16x8 oh, ol;
#pragma unroll
    for (int j = 0; j < 8; j++) {
        float v = Wy[i8 + j];
        oh[j] = f2bf(v);
        ol[j] = f2bf(v - bf2f(oh[j]));
    }
    *(u16x8*)(hi + i8) = oh;
    *(u16x8*)(lo + i8) = ol;
}

__global__ void k_pack_x(const float* __restrict__ x, u16* __restrict__ xb) {
    size_t i8 = ((size_t)blockIdx.x * blockDim.x + threadIdx.x) * 8;
    if (i8 >= (size_t)S_ * B_ * I_) return;
    u16x8 o;
#pragma unroll
    for (int j = 0; j < 8; j++) o[j] = f2bf(x[i8 + j]);
    *(u16x8*)(xb + i8) = o;
}

// ---- one LSTM time step, 2-D (batch x hidden) tiling ------------------------
// Grid: 256 blocks = 64 ng (16 hidden units each) x 4 bg (16 batch rows each).
// blockIdx = bg*64 + ng, so the 4 batch-copies of an ng share ng%8 -> same XCD
// -> the 192 KB weight slice stays L2-resident and is fetched once per XCD.
// Block computes the 16x16x(4 gates) pre-activation patch: wave w takes
// K range [384w,384w+384) (12 chunks of 32; 1 A-load shared by 4 gate B-loads
// per chunk), partials reduced via LDS, then each thread owns one (b,j):
// cell update + h hi/lo store. c state per-block-resident in global fp32.
// Activation broadcast per step: 256 blocks x 48 KB = 12 MB (vs 49 MB in R3).
__global__ __launch_bounds__(256) void k_step3(
    const u16* __restrict__ Wall,   // [4096][1536] bf16
    const u16* __restrict__ xbf,    // [S][64][512] bf16
    const float* __restrict__ bfv, const float* __restrict__ biv,
    const float* __restrict__ bov, const float* __restrict__ bgv,
    u16* __restrict__ hhi,          // [S+1][64][1024] bf16
    u16* __restrict__ hlo,          // [S+1][64][1024] bf16 residual
    float* __restrict__ cst,        // [64][1024] fp32
    int t)
{
    const int tid = threadIdx.x;
    const int w = tid >> 6;          // wave 0..3 -> K range
    const int lane = tid & 63;
    const int la = lane & 15;        // A-row (batch) / B-row (unit) / C-col
    const int q = lane >> 4;         // k sub-offset group / C row group
    const int ng = blockIdx.x & 63;  // hidden group: units [16ng, 16ng+16)
    const int bg = blockIdx.x >> 6;  // batch group: rows [16bg, 16bg+16)

    const u16* xrow = xbf + (size_t)t * (B_ * I_) + (size_t)(bg * 16 + la) * I_;
    const u16* hrow = hhi + (size_t)t * (B_ * H_) + (size_t)(bg * 16 + la) * H_;
    // B row for gate g: Wall[g*H + 16ng + la]
    const u16* br0 = Wall + (size_t)(0 * H_ + ng * 16 + la) * C_;
    const u16* br1 = Wall + (size_t)(1 * H_ + ng * 16 + la) * C_;
    const u16* br2 = Wall + (size_t)(2 * H_ + ng * 16 + la) * C_;
    const u16* br3 = Wall + (size_t)(3 * H_ + ng * 16 + la) * C_;

    f32x4 acc0 = (f32x4){0.f,0.f,0.f,0.f};
    f32x4 acc1 = (f32x4){0.f,0.f,0.f,0.f};
    f32x4 acc2 = (f32x4){0.f,0.f,0.f,0.f};
    f32x4 acc3 = (f32x4){0.f,0.f,0.f,0.f};

    const int kw = w * 384;
#pragma unroll
    for (int c = 0; c < 12; c++) {
        const int k0 = kw + c * 32;              // wave-uniform
        const u16* ap = (k0 < I_) ? (xrow + k0) : (hrow + (k0 - I_));
        bf16x8 aa = *(const bf16x8*)(ap + q * 8);
        bf16x8 b0 = *(const bf16x8*)(br0 + k0 + q * 8);
        bf16x8 b1 = *(const bf16x8*)(br1 + k0 + q * 8);
        bf16x8 b2 = *(const bf16x8*)(br2 + k0 + q * 8);
        bf16x8 b3 = *(const bf16x8*)(br3 + k0 + q * 8);
        acc0 = __builtin_amdgcn_mfma_f32_16x16x32_bf16(aa, b0, acc0, 0, 0, 0);
        acc1 = __builtin_amdgcn_mfma_f32_16x16x32_bf16(aa, b1, acc1, 0, 0, 0);
        acc2 = __builtin_amdgcn_mfma_f32_16x16x32_bf16(aa, b2, acc2, 0, 0, 0);
        acc3 = __builtin_amdgcn_mfma_f32_16x16x32_bf16(aa, b3, acc3, 0, 0, 0);
    }

    // reduce the 4 wave-partials through LDS
    __shared__ float gl[4][4][16][17];   // [wave][gate][m(batch)][n(unit)]
#pragma unroll
    for (int r = 0; r < 4; r++) {
        gl[w][0][q * 4 + r][la] = acc0[r];
        gl[w][1][q * 4 + r][la] = acc1[r];
        gl[w][2][q * 4 + r][la] = acc2[r];
        gl[w][3][q * 4 + r][la] = acc3[r];
    }
    __syncthreads();

    const int m = tid >> 4;          // batch row within tile
    const int n = tid & 15;          // unit within tile
    const int j = ng * 16 + n;
    const int b = bg * 16 + m;
    float s0 = 0.f, s1 = 0.f, s2 = 0.f, s3 = 0.f;
#pragma unroll
    for (int ww = 0; ww < 4; ww++) {
        s0 += gl[ww][0][m][n];
        s1 += gl[ww][1][m][n];
        s2 += gl[ww][2][m][n];
        s3 += gl[ww][3][m][n];
    }
    float fg = sigm(s0 + bfv[j]);
    float ig = sigm(s1 + biv[j]);
    float og = sigm(s2 + bov[j]);
    float gg = tanhf(s3 + bgv[j]);
    float cn = fg * cst[(size_t)b * H_ + j] + ig * gg;
    float hn = og * tanhf(cn);
    cst[(size_t)b * H_ + j] = cn;
    u16 hb = f2bf(hn);
    size_t oa = (size_t)(t + 1) * (B_ * H_) + (size_t)b * H_ + j;
    hhi[oa] = hb;
    hlo[oa] = f2bf(hn - bf2f(hb));
}

// ---- final projection: out = H_all @ Wy^T + by (bf16 hi/lo, ~fp32 quality)
__global__ __launch_bounds__(256) void k_pred(
    const u16* __restrict__ ah, const u16* __restrict__ al,
    const u16* __restrict__ wyh, const u16* __restrict__ wyl,
    const float* __restrict__ by, float* __restrict__ out)
{
    const int tid = threadIdx.x;
    const int wv = tid >> 6;
    const int lane = tid & 63;
    const int la = lane & 15;
    const int kg = (lane >> 4) * 8;
    const int m0 = blockIdx.x * 64;
    const int n0 = blockIdx.y * 64 + wv * 16;

    const u16* bh = wyh + (size_t)(n0 + la) * H_ + kg;
    const u16* bl = wyl + (size_t)(n0 + la) * H_ + kg;

    f32x4 acc[4];
#pragma unroll
    for (int m = 0; m < 4; m++) acc[m] = (f32x4){0.f, 0.f, 0.f, 0.f};

    for (int k = 0; k < H_; k += 32) {
        bf16x8 bhh = *(const bf16x8*)(bh + k);
        bf16x8 bll = *(const bf16x8*)(bl + k);
#pragma unroll
        for (int m = 0; m < 4; m++) {
            size_t arow = (size_t)(m0 + m * 16 + la);
            bf16x8 aa  = *(const bf16x8*)(ah + arow * H_ + k + kg);
            bf16x8 aal = *(const bf16x8*)(al + arow * H_ + k + kg);
            acc[m] = __builtin_amdgcn_mfma_f32_16x16x32_bf16(aal, bhh, acc[m], 0, 0, 0);
            acc[m] = __builtin_amdgcn_mfma_f32_16x16x32_bf16(aa, bll, acc[m], 0, 0, 0);
            acc[m] = __builtin_amdgcn_mfma_f32_16x16x32_bf16(aa, bhh, acc[m], 0, 0, 0);
        }
    }

#pragma unroll
    for (int m = 0; m < 4; m++)
#pragma unroll
        for (int r = 0; r < 4; r++) {
            int row = m0 + m * 16 + (lane >> 4) * 4 + r;
            int col = n0 + la;
            out[(size_t)row * O_ + col] = acc[m][r] + by[col];
        }
}

// ---- host ------------------------------------------------------------------

extern "C" void kernel_launch(void* const* d_in, const int* in_sizes, int n_in,
                              void* d_out, int out_size, void* d_ws, size_t ws_size,
                              hipStream_t stream) {
    const float* x   = (const float*)d_in[0];
    const float* Wf  = (const float*)d_in[1];
    const float* bfv = (const float*)d_in[2];
    const float* Wi  = (const float*)d_in[3];
    const float* biv = (const float*)d_in[4];
    const float* Wo  = (const float*)d_in[5];
    const float* bov = (const float*)d_in[6];
    const float* Wg  = (const float*)d_in[7];
    const float* bgv = (const float*)d_in[8];
    const float* Wy  = (const float*)d_in[9];
    const float* by  = (const float*)d_in[10];
    float* out = (float*)d_out;

    char* ws = (char*)d_ws;
    size_t off = 0;
    auto alloc = [&](size_t bytes) {
        char* p = ws + off;
        off += (bytes + 255) & ~(size_t)255;
        return p;
    };
    u16*   Wall = (u16*)alloc((size_t)NG_ * C_ * 2);
    u16*   Wyhi = (u16*)alloc((size_t)O_ * H_ * 2);
    u16*   Wylo = (u16*)alloc((size_t)O_ * H_ * 2);
    u16*   xbf  = (u16*)alloc((size_t)S_ * B_ * I_ * 2);
    float* cst  = (float*)alloc((size_t)B_ * H_ * 4);
    u16*   hhi  = (u16*)alloc((size_t)(S_ + 1) * B_ * H_ * 2);
    u16*   hlo  = (u16*)alloc((size_t)(S_ + 1) * B_ * H_ * 2);

    (void)hipMemsetAsync(cst, 0, (size_t)B_ * H_ * 4, stream);
    (void)hipMemsetAsync(hhi, 0, (size_t)B_ * H_ * 2, stream);

    k_pack_w <<<3072, 256, 0, stream>>>(Wf, Wi, Wo, Wg, Wall);
    k_pack_wy<<<256,  256, 0, stream>>>(Wy, Wyhi, Wylo);
    k_pack_x <<<8192, 256, 0, stream>>>(x, xbf);

    for (int t = 0; t < S_; t++)
        k_step3<<<256, 256, 0, stream>>>(Wall, xbf, bfv, biv, bov, bgv,
                                         hhi, hlo, cst, t);

    k_pred<<<dim3(512, 8), 256, 0, stream>>>(hhi + (size_t)B_ * H_, hlo + (size_t)B_ * H_,
                                             Wyhi, Wylo, by, out);
}